// Round 10
// baseline (902.692 us; speedup 1.0000x reference)
//
#include <hip/hip_runtime.h>

// ---------------------------------------------------------------------------
// 6-layer GCN. Layer l: y = b + D^-1/2(A+I)D^-1/2 h ; x_next = lrelu(y)
// R9: hs/xact in SLICE-MAJOR layout [2][N][32] (each 12.8MB slice contiguous
//     -> memory-side granules are slice-private). Agg blocks pinned:
//     (blockIdx&7)>>2 == slice (XCDs 0-3 -> slice 0, 4-7 -> slice 1).
//     Wave = one dst row, 64 lanes = 2 edges x 32 feats, 16-edge unroll
//     (8 gather instrs = 16x128B segments in flight). lrelu in agg epilogue;
//     hs = dinv.*h prescaled.
// d_ws layout: rowptr[N+1] | dinv[N] | ssrc[E] | bufA[64N] | bufB[64N]
// Build temps alias into bufA (released before layer 0 writes bufA).
// ---------------------------------------------------------------------------

__device__ __forceinline__ float readlane_f(float v, int l) {
    union { float f; int i; } u;
    u.f = v;
    u.i = __builtin_amdgcn_readlane(u.i, l);
    return u.f;
}

// --- pass 1: coarse histogram of dst>>7 into NB buckets ---------------------
__global__ __launch_bounds__(256) void bucket_hist(const int* __restrict__ dst,
                                                   int* __restrict__ ghist,
                                                   int E, int NB) {
    __shared__ int h[1024];
    for (int i = threadIdx.x; i < NB; i += 256) h[i] = 0;
    __syncthreads();
    int i = blockIdx.x * blockDim.x + threadIdx.x;
    int stride = gridDim.x * blockDim.x;
    for (; i < E; i += stride) atomicAdd(&h[dst[i] >> 7], 1);
    __syncthreads();
    for (int j = threadIdx.x; j < NB; j += 256) {
        int c = h[j];
        if (c) atomicAdd(&ghist[j], c);
    }
}

// --- pass 2: exclusive scan of bucket counts (single block, 1024 thr) -------
__global__ void bucket_scan(const int* __restrict__ ghist, int* __restrict__ base,
                            int* __restrict__ cursor, int NB, int E) {
    int tid = threadIdx.x, lane = tid & 63, wid = tid >> 6;
    int v = (tid < NB) ? ghist[tid] : 0;
    int incl = v;
#pragma unroll
    for (int off = 1; off < 64; off <<= 1) {
        int t = __shfl_up(incl, off);
        if (lane >= off) incl += t;
    }
    __shared__ int ws[16];
    if (lane == 63) ws[wid] = incl;
    __syncthreads();
    if (tid == 0) {
        int run = 0;
        for (int i = 0; i < 16; ++i) { int t = ws[i]; ws[i] = run; run += t; }
    }
    __syncthreads();
    int excl = ws[wid] + incl - v;
    if (tid < NB) { base[tid] = excl; cursor[tid] = excl; }
    if (tid == 0) base[NB] = E;
}

// --- pass 3: scatter edges into bucket-sorted (bsrc, bdl) -------------------
__global__ __launch_bounds__(256) void bucket_scatter(
    const int* __restrict__ src, const int* __restrict__ dst,
    int* __restrict__ cursor, int* __restrict__ bsrc,
    unsigned char* __restrict__ bdl, int E, int NB) {
    __shared__ int h[1024];
    __shared__ int rb[1024];
    const int CH = 4096;
    for (int c0 = blockIdx.x * CH; c0 < E; c0 += gridDim.x * CH) {
        int cend = c0 + CH < E ? c0 + CH : E;
        for (int j = threadIdx.x; j < NB; j += 256) h[j] = 0;
        __syncthreads();
        for (int i = c0 + threadIdx.x; i < cend; i += 256)
            atomicAdd(&h[dst[i] >> 7], 1);
        __syncthreads();
        for (int j = threadIdx.x; j < NB; j += 256) {
            int c = h[j];
            rb[j] = c ? atomicAdd(&cursor[j], c) : 0;
            h[j] = 0;
        }
        __syncthreads();
        for (int i = c0 + threadIdx.x; i < cend; i += 256) {
            int d = dst[i];
            int b = d >> 7;
            int p = rb[b] + atomicAdd(&h[b], 1);
            bsrc[p] = src[i];
            bdl[p] = (unsigned char)(d & 127);
        }
        __syncthreads();
    }
}

// --- pass 4: per-bucket CSR finalize: rowptr, dinv, ssrc --------------------
__global__ __launch_bounds__(256) void bucket_finalize(
    const int* __restrict__ base, const int* __restrict__ bsrc,
    const unsigned char* __restrict__ bdl, int* __restrict__ rowptr,
    int* __restrict__ ssrc, float* __restrict__ dinv, int N, int NB, int E) {
    __shared__ int cnt[128];
    __shared__ int cur[128];
    __shared__ int w0sum;
    const int tid = threadIdx.x;
    const int lane = tid & 63;
    for (int b = blockIdx.x; b < NB; b += gridDim.x) {
        const int s = base[b], e = base[b + 1];
        const int d0 = b << 7;
        const int w = (N - d0 < 128) ? (N - d0) : 128;
        if (tid < 128) cnt[tid] = 0;
        __syncthreads();
        for (int i = s + tid; i < e; i += 256) atomicAdd(&cnt[bdl[i]], 1);
        __syncthreads();
        int v = (tid < 128) ? cnt[tid] : 0;
        int incl = v;
#pragma unroll
        for (int off = 1; off < 64; off <<= 1) {
            int t = __shfl_up(incl, off);
            if (lane >= off) incl += t;
        }
        if (tid == 63) w0sum = incl;
        __syncthreads();
        int excl = incl - v + ((tid >= 64 && tid < 128) ? w0sum : 0);
        if (tid < 128) cur[tid] = s + excl;
        if (tid < w) {
            rowptr[d0 + tid] = s + excl;
            dinv[d0 + tid] = rsqrtf((float)(v + 1));   // +1 self loop
        }
        __syncthreads();
        for (int i = s + tid; i < e; i += 256) {
            int p = atomicAdd(&cur[bdl[i]], 1);
            ssrc[p] = bsrc[i];
        }
        __syncthreads();
    }
    if (blockIdx.x == 0 && tid == 0) rowptr[N] = E;
}

// --- dense transform + dinv pre-scale, slice-major in/out:
//   hsS[l>>5][row][l&31] = dinv[row] * sum_k in(row,k) * W[k,l]
// IN_SLICED: in is [2][n][32] (pre-activated); else row-major [n][K] raw x.
template <int K, bool IN_SLICED>
__global__ __launch_bounds__(256) void gemm_hs(
    const float* __restrict__ in, const float* __restrict__ W,
    const float* __restrict__ dinv, float* __restrict__ hsS, int n) {
    const int lane = threadIdx.x & 63;
    const int gw = blockIdx.x * (blockDim.x >> 6) + (threadIdx.x >> 6);
    const int nw = gridDim.x * (blockDim.x >> 6);
    const size_t slot = (size_t)(lane >> 5) * n * 32 + (lane & 31);

    float wreg[K];
#pragma unroll
    for (int k = 0; k < K; ++k) wreg[k] = W[k * 64 + lane];

    for (int row = gw; row < n; row += nw) {
        float xv0, xv1 = 0.f;
        if (IN_SLICED) {
            xv0 = in[slot + (size_t)row * 32];
        } else {
            xv0 = in[(size_t)row * K + lane];
            if (K == 128) xv1 = in[(size_t)row * K + 64 + lane];
        }
        float a0 = 0.f, a1 = 0.f, a2 = 0.f, a3 = 0.f;
#pragma unroll
        for (int k = 0; k < 64; k += 4) {
            a0 = fmaf(readlane_f(xv0, k + 0), wreg[k + 0], a0);
            a1 = fmaf(readlane_f(xv0, k + 1), wreg[k + 1], a1);
            a2 = fmaf(readlane_f(xv0, k + 2), wreg[k + 2], a2);
            a3 = fmaf(readlane_f(xv0, k + 3), wreg[k + 3], a3);
        }
        if (K == 128) {
#pragma unroll
            for (int k = 0; k < 64; k += 4) {
                a0 = fmaf(readlane_f(xv1, k + 0), wreg[64 + k + 0], a0);
                a1 = fmaf(readlane_f(xv1, k + 1), wreg[64 + k + 1], a1);
                a2 = fmaf(readlane_f(xv1, k + 2), wreg[64 + k + 2], a2);
                a3 = fmaf(readlane_f(xv1, k + 3), wreg[64 + k + 3], a3);
            }
        }
        float acc = (a0 + a1) + (a2 + a3);
        hsS[slot + (size_t)row * 32] = dinv[row] * acc;
    }
}

// --- sliced aggregation: slice = (blockIdx&7)>>2 (pinned to an XCD group),
//     wave = one dst row, lanes = 2 edges (g) x 32 feats (f), 16-edge unroll.
//     Stores xactS = lrelu(b + dinv[d]*(self + sum)) in slice-major layout.
__global__ __launch_bounds__(256) void csr_agg_slice(
    const float* __restrict__ hsS, const int* __restrict__ rowptr,
    const int* __restrict__ ssrc, const float* __restrict__ dinv,
    const float* __restrict__ b, float* __restrict__ xactS, int N) {
    const int lane = threadIdx.x & 63;
    const int wid = threadIdx.x >> 6;            // 0..3
    const int sl = (blockIdx.x & 7) >> 2;        // slice 0/1
    const int sb = (blockIdx.x >> 3) * 4 + (blockIdx.x & 3);  // block idx in slice
    const int w = sb * 4 + wid;                  // wave idx in slice
    const int nw = (gridDim.x >> 1) * 4;         // waves per slice
    const int g = lane >> 5;                     // edge in pair
    const int f = lane & 31;
    const float* __restrict__ hs = hsS + (size_t)sl * N * 32;
    float* __restrict__ xact = xactS + (size_t)sl * N * 32;
    const float bl = b[sl * 32 + f];

    for (int d = w; d < N; d += nw) {
        int e = __builtin_amdgcn_readfirstlane(rowptr[d]);
        const int end = __builtin_amdgcn_readfirstlane(rowptr[d + 1]);
        float acc0 = (g == 0) ? hs[(size_t)d * 32 + f] : 0.f;   // self loop
        float acc1 = 0.f;
        for (; e + 16 <= end; e += 16) {
            int s0 = __builtin_nontemporal_load(ssrc + e + 0 + g);
            int s1 = __builtin_nontemporal_load(ssrc + e + 2 + g);
            int s2 = __builtin_nontemporal_load(ssrc + e + 4 + g);
            int s3 = __builtin_nontemporal_load(ssrc + e + 6 + g);
            int s4 = __builtin_nontemporal_load(ssrc + e + 8 + g);
            int s5 = __builtin_nontemporal_load(ssrc + e + 10 + g);
            int s6 = __builtin_nontemporal_load(ssrc + e + 12 + g);
            int s7 = __builtin_nontemporal_load(ssrc + e + 14 + g);
            float v0 = hs[(size_t)s0 * 32 + f];
            float v1 = hs[(size_t)s1 * 32 + f];
            float v2 = hs[(size_t)s2 * 32 + f];
            float v3 = hs[(size_t)s3 * 32 + f];
            float v4 = hs[(size_t)s4 * 32 + f];
            float v5 = hs[(size_t)s5 * 32 + f];
            float v6 = hs[(size_t)s6 * 32 + f];
            float v7 = hs[(size_t)s7 * 32 + f];
            acc0 += v0 + v2;
            acc1 += v1 + v3;
            acc0 += v4 + v6;
            acc1 += v5 + v7;
        }
        for (; e + 2 <= end; e += 2) {
            int s = __builtin_nontemporal_load(ssrc + e + g);
            acc0 += hs[(size_t)s * 32 + f];
        }
        if (e + g < end) {
            int s = __builtin_nontemporal_load(ssrc + e + g);
            acc1 += hs[(size_t)s * 32 + f];
        }
        float acc = acc0 + acc1;
        acc += __shfl_xor(acc, 32);              // merge the two edge groups
        float y = fmaf(dinv[d], acc, bl);
        y = y >= 0.f ? y : 0.2f * y;             // lrelu folded here
        if (g == 0) xact[(size_t)d * 32 + f] = y;
    }
}

// --- final layer gemm: slice-major xact -> W5[64,4] -> dinv scale -----------
__global__ __launch_bounds__(256) void gemm4_hs(
    const float* __restrict__ xactS, const float* __restrict__ W,  // [64,4]
    const float* __restrict__ dinv, float* __restrict__ hs4, int n) {
    int i = blockIdx.x * blockDim.x + threadIdx.x;
    int stride = gridDim.x * blockDim.x;
    for (; i < n; i += stride) {
        float a0 = 0.f, a1 = 0.f, a2 = 0.f, a3 = 0.f;
#pragma unroll
        for (int sl = 0; sl < 2; ++sl) {
            const float4* xr = (const float4*)(xactS + (size_t)sl * n * 32 + (size_t)i * 32);
#pragma unroll
            for (int k4 = 0; k4 < 8; ++k4) {
                float4 xv = xr[k4];
                int k = sl * 32 + k4 * 4;
                a0 = fmaf(xv.x, W[(k + 0) * 4 + 0], a0); a1 = fmaf(xv.x, W[(k + 0) * 4 + 1], a1);
                a2 = fmaf(xv.x, W[(k + 0) * 4 + 2], a2); a3 = fmaf(xv.x, W[(k + 0) * 4 + 3], a3);
                a0 = fmaf(xv.y, W[(k + 1) * 4 + 0], a0); a1 = fmaf(xv.y, W[(k + 1) * 4 + 1], a1);
                a2 = fmaf(xv.y, W[(k + 1) * 4 + 2], a2); a3 = fmaf(xv.y, W[(k + 1) * 4 + 3], a3);
                a0 = fmaf(xv.z, W[(k + 2) * 4 + 0], a0); a1 = fmaf(xv.z, W[(k + 2) * 4 + 1], a1);
                a2 = fmaf(xv.z, W[(k + 2) * 4 + 2], a2); a3 = fmaf(xv.z, W[(k + 2) * 4 + 3], a3);
                a0 = fmaf(xv.w, W[(k + 3) * 4 + 0], a0); a1 = fmaf(xv.w, W[(k + 3) * 4 + 1], a1);
                a2 = fmaf(xv.w, W[(k + 3) * 4 + 2], a2); a3 = fmaf(xv.w, W[(k + 3) * 4 + 3], a3);
            }
        }
        float di = dinv[i];
        ((float4*)hs4)[i] = make_float4(di * a0, di * a1, di * a2, di * a3);
    }
}

// --- final aggregation over pre-scaled hs4: out = b + dinv[d]*(self + sum) --
__global__ __launch_bounds__(256) void csr_agg4(
    const float* __restrict__ hs4, const int* __restrict__ rowptr,
    const int* __restrict__ ssrc, const float* __restrict__ dinv,
    const float* __restrict__ b, float* __restrict__ out, int n) {
    int i = blockIdx.x * blockDim.x + threadIdx.x;
    int stride = gridDim.x * blockDim.x;
    float b0 = b[0], b1 = b[1], b2 = b[2], b3 = b[3];
    for (; i < n; i += stride) {
        float4 hv = ((const float4*)hs4)[i];
        float a0 = hv.x, a1 = hv.y, a2 = hv.z, a3 = hv.w;   // self loop
        int e = rowptr[i], end = rowptr[i + 1];
        for (; e < end; ++e) {
            int s = ssrc[e];
            float4 v = ((const float4*)hs4)[s];
            a0 += v.x; a1 += v.y; a2 += v.z; a3 += v.w;
        }
        float di = dinv[i];
        ((float4*)out)[i] = make_float4(fmaf(di, a0, b0), fmaf(di, a1, b1),
                                        fmaf(di, a2, b2), fmaf(di, a3, b3));
    }
}

static inline size_t al64(size_t x) { return (x + 63) & ~(size_t)63; }

extern "C" void kernel_launch(void* const* d_in, const int* in_sizes, int n_in,
                              void* d_out, int out_size, void* d_ws, size_t ws_size,
                              hipStream_t stream) {
    const float* x  = (const float*)d_in[0];
    const int* ei   = (const int*)d_in[1];
    const float* W0 = (const float*)d_in[2];
    const float* b0 = (const float*)d_in[3];
    const float* W1 = (const float*)d_in[4];
    const float* b1 = (const float*)d_in[5];
    const float* W2 = (const float*)d_in[6];
    const float* b2 = (const float*)d_in[7];
    const float* W3 = (const float*)d_in[8];
    const float* b3 = (const float*)d_in[9];
    const float* W4 = (const float*)d_in[10];
    const float* b4 = (const float*)d_in[11];
    const float* W5 = (const float*)d_in[12];
    const float* b5 = (const float*)d_in[13];

    const int N = in_sizes[0] / 128;
    const int E = in_sizes[1] / 2;
    const int* src  = ei;       // edge_index[0] = message sources
    const int* dstp = ei + E;   // edge_index[1] = aggregation targets
    const int NB = (N + 127) >> 7;   // dst buckets of 128 ids (NB <= 1024)

    float* ws = (float*)d_ws;
    size_t off = 0;
    int*   rowptr = (int*)(ws + off);   off += al64((size_t)N + 1);
    float* dinv   = ws + off;           off += al64((size_t)N);
    int*   ssrc   = (int*)(ws + off);   off += al64((size_t)E);
    float* bufA   = ws + off;           off += (size_t)64 * N;
    float* bufB   = ws + off;

    // build temps alias into bufA (released before layer 0 writes bufA)
    int* ghist = (int*)bufA;                       // [1024]
    int* bbase = ghist + 1024;                     // [NB+1]
    int* bcur  = bbase + 1088;                     // [NB]
    int* bsrc  = (int*)(bufA + 4096);              // [E]
    unsigned char* bdl = (unsigned char*)(bsrc + E);  // [E]

    // ---- graph build (bucketed counting sort) ----
    hipMemsetAsync(ghist, 0, 1024 * sizeof(int), stream);
    bucket_hist<<<391, 256, 0, stream>>>(dstp, ghist, E, NB);
    bucket_scan<<<1, 1024, 0, stream>>>(ghist, bbase, bcur, NB, E);
    bucket_scatter<<<391, 256, 0, stream>>>(src, dstp, bcur, bsrc, bdl, E, NB);
    bucket_finalize<<<NB, 256, 0, stream>>>(bbase, bsrc, bdl, rowptr, ssrc, dinv, N, NB, E);

    const int AGG_BLOCKS = 2048;   // multiple of 8; 1024 blocks per slice

    // ---- layer 0: x[N,128] row-major -> hs0 sliced ----
    gemm_hs<128, false><<<2048, 256, 0, stream>>>(x, W0, dinv, bufA, N);
    csr_agg_slice<<<AGG_BLOCKS, 256, 0, stream>>>(bufA, rowptr, ssrc, dinv, b0, bufB, N);

    // ---- layers 1-4 (sliced xact in bufB -> sliced hs in bufA -> ...) ----
    const float* Ws[4] = {W1, W2, W3, W4};
    const float* bs[4] = {b1, b2, b3, b4};
    for (int l = 0; l < 4; ++l) {
        gemm_hs<64, true><<<2048, 256, 0, stream>>>(bufB, Ws[l], dinv, bufA, N);
        csr_agg_slice<<<AGG_BLOCKS, 256, 0, stream>>>(bufA, rowptr, ssrc, dinv, bs[l], bufB, N);
    }

    // ---- layer 5: sliced xact -> hs4[N,4] -> out ----
    gemm4_hs<<<1024, 256, 0, stream>>>(bufB, W5, dinv, bufA, N);
    csr_agg4<<<1024, 256, 0, stream>>>(bufA, rowptr, ssrc, dinv, b5, (float*)d_out, N);
}

// Round 11
// 574.625 us; speedup vs baseline: 1.5709x; 1.5709x over previous
//
#include <hip/hip_runtime.h>

// ---------------------------------------------------------------------------
// 6-layer GCN. Layer l: y = b + D^-1/2(A+I)D^-1/2 h ; x_next = lrelu(y)
// R10: row-major agg with WIDE gathers: 64 lanes = 4 edges x 16 lanes,
//      each lane loads float4 (16B) -> 1 vmem instr covers 4 edges (4x fewer
//      requests than R2/R5, same bytes). 4-deep unroll = 16 edges in flight.
//      Cross-edge reduce via 8 shfl_xor. lrelu folded in agg epilogue;
//      hs = dinv.*h prescaled in gemm epilogue. R2 build, R5 gemm.
// d_ws layout: rowptr[N+1] | dinv[N] | ssrc[E] | bufA[64N] | bufB[64N]
// Build temps alias into bufA (released before layer 0 writes bufA).
// ---------------------------------------------------------------------------

__device__ __forceinline__ float readlane_f(float v, int l) {
    union { float f; int i; } u;
    u.f = v;
    u.i = __builtin_amdgcn_readlane(u.i, l);
    return u.f;
}

// --- pass 1: coarse histogram of dst>>7 into NB buckets ---------------------
__global__ __launch_bounds__(256) void bucket_hist(const int* __restrict__ dst,
                                                   int* __restrict__ ghist,
                                                   int E, int NB) {
    __shared__ int h[1024];
    for (int i = threadIdx.x; i < NB; i += 256) h[i] = 0;
    __syncthreads();
    int i = blockIdx.x * blockDim.x + threadIdx.x;
    int stride = gridDim.x * blockDim.x;
    for (; i < E; i += stride) atomicAdd(&h[dst[i] >> 7], 1);
    __syncthreads();
    for (int j = threadIdx.x; j < NB; j += 256) {
        int c = h[j];
        if (c) atomicAdd(&ghist[j], c);
    }
}

// --- pass 2: exclusive scan of bucket counts (single block, 1024 thr) -------
__global__ void bucket_scan(const int* __restrict__ ghist, int* __restrict__ base,
                            int* __restrict__ cursor, int NB, int E) {
    int tid = threadIdx.x, lane = tid & 63, wid = tid >> 6;
    int v = (tid < NB) ? ghist[tid] : 0;
    int incl = v;
#pragma unroll
    for (int off = 1; off < 64; off <<= 1) {
        int t = __shfl_up(incl, off);
        if (lane >= off) incl += t;
    }
    __shared__ int ws[16];
    if (lane == 63) ws[wid] = incl;
    __syncthreads();
    if (tid == 0) {
        int run = 0;
        for (int i = 0; i < 16; ++i) { int t = ws[i]; ws[i] = run; run += t; }
    }
    __syncthreads();
    int excl = ws[wid] + incl - v;
    if (tid < NB) { base[tid] = excl; cursor[tid] = excl; }
    if (tid == 0) base[NB] = E;
}

// --- pass 3: scatter edges into bucket-sorted (bsrc, bdl) -------------------
__global__ __launch_bounds__(256) void bucket_scatter(
    const int* __restrict__ src, const int* __restrict__ dst,
    int* __restrict__ cursor, int* __restrict__ bsrc,
    unsigned char* __restrict__ bdl, int E, int NB) {
    __shared__ int h[1024];
    __shared__ int rb[1024];
    const int CH = 4096;
    for (int c0 = blockIdx.x * CH; c0 < E; c0 += gridDim.x * CH) {
        int cend = c0 + CH < E ? c0 + CH : E;
        for (int j = threadIdx.x; j < NB; j += 256) h[j] = 0;
        __syncthreads();
        for (int i = c0 + threadIdx.x; i < cend; i += 256)
            atomicAdd(&h[dst[i] >> 7], 1);
        __syncthreads();
        for (int j = threadIdx.x; j < NB; j += 256) {
            int c = h[j];
            rb[j] = c ? atomicAdd(&cursor[j], c) : 0;
            h[j] = 0;
        }
        __syncthreads();
        for (int i = c0 + threadIdx.x; i < cend; i += 256) {
            int d = dst[i];
            int b = d >> 7;
            int p = rb[b] + atomicAdd(&h[b], 1);
            bsrc[p] = src[i];
            bdl[p] = (unsigned char)(d & 127);
        }
        __syncthreads();
    }
}

// --- pass 4: per-bucket CSR finalize: rowptr, dinv, ssrc --------------------
__global__ __launch_bounds__(256) void bucket_finalize(
    const int* __restrict__ base, const int* __restrict__ bsrc,
    const unsigned char* __restrict__ bdl, int* __restrict__ rowptr,
    int* __restrict__ ssrc, float* __restrict__ dinv, int N, int NB, int E) {
    __shared__ int cnt[128];
    __shared__ int cur[128];
    __shared__ int w0sum;
    const int tid = threadIdx.x;
    const int lane = tid & 63;
    for (int b = blockIdx.x; b < NB; b += gridDim.x) {
        const int s = base[b], e = base[b + 1];
        const int d0 = b << 7;
        const int w = (N - d0 < 128) ? (N - d0) : 128;
        if (tid < 128) cnt[tid] = 0;
        __syncthreads();
        for (int i = s + tid; i < e; i += 256) atomicAdd(&cnt[bdl[i]], 1);
        __syncthreads();
        int v = (tid < 128) ? cnt[tid] : 0;
        int incl = v;
#pragma unroll
        for (int off = 1; off < 64; off <<= 1) {
            int t = __shfl_up(incl, off);
            if (lane >= off) incl += t;
        }
        if (tid == 63) w0sum = incl;
        __syncthreads();
        int excl = incl - v + ((tid >= 64 && tid < 128) ? w0sum : 0);
        if (tid < 128) cur[tid] = s + excl;
        if (tid < w) {
            rowptr[d0 + tid] = s + excl;
            dinv[d0 + tid] = rsqrtf((float)(v + 1));   // +1 self loop
        }
        __syncthreads();
        for (int i = s + tid; i < e; i += 256) {
            int p = atomicAdd(&cur[bdl[i]], 1);
            ssrc[p] = bsrc[i];
        }
        __syncthreads();
    }
    if (blockIdx.x == 0 && tid == 0) rowptr[N] = E;
}

// --- dense transform + dinv pre-scale (readlane broadcast, row-major):
//   hs[row,l] = dinv[row] * sum_k in[row,k] * W[k,l]
// `in` is pre-activated (agg applies lrelu) or raw x for layer 0.
template <int K>
__global__ __launch_bounds__(256) void gemm_hs(
    const float* __restrict__ in, const float* __restrict__ W,
    const float* __restrict__ dinv, float* __restrict__ hs, int n) {
    const int lane = threadIdx.x & 63;
    const int gw = blockIdx.x * (blockDim.x >> 6) + (threadIdx.x >> 6);
    const int nw = gridDim.x * (blockDim.x >> 6);

    float wreg[K];
#pragma unroll
    for (int k = 0; k < K; ++k) wreg[k] = W[k * 64 + lane];

    for (int row = gw; row < n; row += nw) {
        float xv0 = in[(size_t)row * K + lane];
        float xv1 = 0.f;
        if (K == 128) xv1 = in[(size_t)row * K + 64 + lane];
        float a0 = 0.f, a1 = 0.f, a2 = 0.f, a3 = 0.f;
#pragma unroll
        for (int k = 0; k < 64; k += 4) {
            a0 = fmaf(readlane_f(xv0, k + 0), wreg[k + 0], a0);
            a1 = fmaf(readlane_f(xv0, k + 1), wreg[k + 1], a1);
            a2 = fmaf(readlane_f(xv0, k + 2), wreg[k + 2], a2);
            a3 = fmaf(readlane_f(xv0, k + 3), wreg[k + 3], a3);
        }
        if (K == 128) {
#pragma unroll
            for (int k = 0; k < 64; k += 4) {
                a0 = fmaf(readlane_f(xv1, k + 0), wreg[64 + k + 0], a0);
                a1 = fmaf(readlane_f(xv1, k + 1), wreg[64 + k + 1], a1);
                a2 = fmaf(readlane_f(xv1, k + 2), wreg[64 + k + 2], a2);
                a3 = fmaf(readlane_f(xv1, k + 3), wreg[64 + k + 3], a3);
            }
        }
        float acc = (a0 + a1) + (a2 + a3);
        hs[(size_t)row * 64 + lane] = dinv[row] * acc;
    }
}

// --- aggregation with wide gathers: wave = dst row, 64 lanes = 4 edges (g)
//     x 16 float4-chunks (c). One vmem instr = 4 edges' 256B rows.
//     Stores x_next = lrelu(b + dinv[d]*(self + sum)).
__global__ __launch_bounds__(256) void csr_agg_f4(
    const float* __restrict__ hs, const int* __restrict__ rowptr,
    const int* __restrict__ ssrc, const float* __restrict__ dinv,
    const float* __restrict__ b, float* __restrict__ xact, int N) {
    const int lane = threadIdx.x & 63;
    const int g = lane >> 4;         // edge slot 0..3
    const int c = lane & 15;         // float4 chunk 0..15
    const int w = blockIdx.x * 4 + (threadIdx.x >> 6);
    const int nw = gridDim.x * 4;
    const float4 bl = ((const float4*)b)[c];

    for (int d = w; d < N; d += nw) {
        int e = __builtin_amdgcn_readfirstlane(rowptr[d]);
        const int end = __builtin_amdgcn_readfirstlane(rowptr[d + 1]);
        float4 a0 = make_float4(0.f, 0.f, 0.f, 0.f), a1 = a0;
        if (g == 0) a0 = ((const float4*)(hs + (size_t)d * 64))[c];  // self loop
        for (; e + 16 <= end; e += 16) {
            int s0 = __builtin_nontemporal_load(ssrc + e + g);
            int s1 = __builtin_nontemporal_load(ssrc + e + 4 + g);
            int s2 = __builtin_nontemporal_load(ssrc + e + 8 + g);
            int s3 = __builtin_nontemporal_load(ssrc + e + 12 + g);
            float4 v0 = ((const float4*)(hs + (size_t)s0 * 64))[c];
            float4 v1 = ((const float4*)(hs + (size_t)s1 * 64))[c];
            float4 v2 = ((const float4*)(hs + (size_t)s2 * 64))[c];
            float4 v3 = ((const float4*)(hs + (size_t)s3 * 64))[c];
            a0.x += v0.x; a0.y += v0.y; a0.z += v0.z; a0.w += v0.w;
            a1.x += v1.x; a1.y += v1.y; a1.z += v1.z; a1.w += v1.w;
            a0.x += v2.x; a0.y += v2.y; a0.z += v2.z; a0.w += v2.w;
            a1.x += v3.x; a1.y += v3.y; a1.z += v3.z; a1.w += v3.w;
        }
        for (; e < end; e += 4) {
            int idx = e + g;
            if (idx < end) {
                int s = __builtin_nontemporal_load(ssrc + idx);
                float4 v = ((const float4*)(hs + (size_t)s * 64))[c];
                a0.x += v.x; a0.y += v.y; a0.z += v.z; a0.w += v.w;
            }
        }
        float4 acc = make_float4(a0.x + a1.x, a0.y + a1.y, a0.z + a1.z, a0.w + a1.w);
        // reduce over the 4 edge groups (lane ^16, ^32)
        acc.x += __shfl_xor(acc.x, 16); acc.y += __shfl_xor(acc.y, 16);
        acc.z += __shfl_xor(acc.z, 16); acc.w += __shfl_xor(acc.w, 16);
        acc.x += __shfl_xor(acc.x, 32); acc.y += __shfl_xor(acc.y, 32);
        acc.z += __shfl_xor(acc.z, 32); acc.w += __shfl_xor(acc.w, 32);
        const float di = dinv[d];
        float4 y;
        y.x = fmaf(di, acc.x, bl.x); y.y = fmaf(di, acc.y, bl.y);
        y.z = fmaf(di, acc.z, bl.z); y.w = fmaf(di, acc.w, bl.w);
        y.x = y.x >= 0.f ? y.x : 0.2f * y.x;
        y.y = y.y >= 0.f ? y.y : 0.2f * y.y;
        y.z = y.z >= 0.f ? y.z : 0.2f * y.z;
        y.w = y.w >= 0.f ? y.w : 0.2f * y.w;
        if (g == 0) ((float4*)(xact + (size_t)d * 64))[c] = y;
    }
}

// --- final layer gemm: pre-activated x -> W5[64,4] -> dinv scale ------------
__global__ __launch_bounds__(256) void gemm4_hs(
    const float* __restrict__ xact, const float* __restrict__ W,  // [64,4]
    const float* __restrict__ dinv, float* __restrict__ hs4, int n) {
    int i = blockIdx.x * blockDim.x + threadIdx.x;
    int stride = gridDim.x * blockDim.x;
    for (; i < n; i += stride) {
        const float4* xr = (const float4*)(xact + (size_t)i * 64);
        float a0 = 0.f, a1 = 0.f, a2 = 0.f, a3 = 0.f;
#pragma unroll
        for (int k4 = 0; k4 < 16; ++k4) {
            float4 xv = xr[k4];
            int k = k4 * 4;
            a0 = fmaf(xv.x, W[(k + 0) * 4 + 0], a0); a1 = fmaf(xv.x, W[(k + 0) * 4 + 1], a1);
            a2 = fmaf(xv.x, W[(k + 0) * 4 + 2], a2); a3 = fmaf(xv.x, W[(k + 0) * 4 + 3], a3);
            a0 = fmaf(xv.y, W[(k + 1) * 4 + 0], a0); a1 = fmaf(xv.y, W[(k + 1) * 4 + 1], a1);
            a2 = fmaf(xv.y, W[(k + 1) * 4 + 2], a2); a3 = fmaf(xv.y, W[(k + 1) * 4 + 3], a3);
            a0 = fmaf(xv.z, W[(k + 2) * 4 + 0], a0); a1 = fmaf(xv.z, W[(k + 2) * 4 + 1], a1);
            a2 = fmaf(xv.z, W[(k + 2) * 4 + 2], a2); a3 = fmaf(xv.z, W[(k + 2) * 4 + 3], a3);
            a0 = fmaf(xv.w, W[(k + 3) * 4 + 0], a0); a1 = fmaf(xv.w, W[(k + 3) * 4 + 1], a1);
            a2 = fmaf(xv.w, W[(k + 3) * 4 + 2], a2); a3 = fmaf(xv.w, W[(k + 3) * 4 + 3], a3);
        }
        float di = dinv[i];
        ((float4*)hs4)[i] = make_float4(di * a0, di * a1, di * a2, di * a3);
    }
}

// --- final aggregation over pre-scaled hs4: out = b + dinv[d]*(self + sum) --
__global__ __launch_bounds__(256) void csr_agg4(
    const float* __restrict__ hs4, const int* __restrict__ rowptr,
    const int* __restrict__ ssrc, const float* __restrict__ dinv,
    const float* __restrict__ b, float* __restrict__ out, int n) {
    int i = blockIdx.x * blockDim.x + threadIdx.x;
    int stride = gridDim.x * blockDim.x;
    float b0 = b[0], b1 = b[1], b2 = b[2], b3 = b[3];
    for (; i < n; i += stride) {
        float4 hv = ((const float4*)hs4)[i];
        float a0 = hv.x, a1 = hv.y, a2 = hv.z, a3 = hv.w;   // self loop
        int e = rowptr[i], end = rowptr[i + 1];
        for (; e < end; ++e) {
            int s = ssrc[e];
            float4 v = ((const float4*)hs4)[s];
            a0 += v.x; a1 += v.y; a2 += v.z; a3 += v.w;
        }
        float di = dinv[i];
        ((float4*)out)[i] = make_float4(fmaf(di, a0, b0), fmaf(di, a1, b1),
                                        fmaf(di, a2, b2), fmaf(di, a3, b3));
    }
}

static inline size_t al64(size_t x) { return (x + 63) & ~(size_t)63; }

extern "C" void kernel_launch(void* const* d_in, const int* in_sizes, int n_in,
                              void* d_out, int out_size, void* d_ws, size_t ws_size,
                              hipStream_t stream) {
    const float* x  = (const float*)d_in[0];
    const int* ei   = (const int*)d_in[1];
    const float* W0 = (const float*)d_in[2];
    const float* b0 = (const float*)d_in[3];
    const float* W1 = (const float*)d_in[4];
    const float* b1 = (const float*)d_in[5];
    const float* W2 = (const float*)d_in[6];
    const float* b2 = (const float*)d_in[7];
    const float* W3 = (const float*)d_in[8];
    const float* b3 = (const float*)d_in[9];
    const float* W4 = (const float*)d_in[10];
    const float* b4 = (const float*)d_in[11];
    const float* W5 = (const float*)d_in[12];
    const float* b5 = (const float*)d_in[13];

    const int N = in_sizes[0] / 128;
    const int E = in_sizes[1] / 2;
    const int* src  = ei;       // edge_index[0] = message sources
    const int* dstp = ei + E;   // edge_index[1] = aggregation targets
    const int NB = (N + 127) >> 7;   // dst buckets of 128 ids (NB <= 1024)

    float* ws = (float*)d_ws;
    size_t off = 0;
    int*   rowptr = (int*)(ws + off);   off += al64((size_t)N + 1);
    float* dinv   = ws + off;           off += al64((size_t)N);
    int*   ssrc   = (int*)(ws + off);   off += al64((size_t)E);
    float* bufA   = ws + off;           off += (size_t)64 * N;
    float* bufB   = ws + off;

    // build temps alias into bufA (released before layer 0 writes bufA)
    int* ghist = (int*)bufA;                       // [1024]
    int* bbase = ghist + 1024;                     // [NB+1]
    int* bcur  = bbase + 1088;                     // [NB]
    int* bsrc  = (int*)(bufA + 4096);              // [E]
    unsigned char* bdl = (unsigned char*)(bsrc + E);  // [E]

    // ---- graph build (bucketed counting sort) ----
    hipMemsetAsync(ghist, 0, 1024 * sizeof(int), stream);
    bucket_hist<<<391, 256, 0, stream>>>(dstp, ghist, E, NB);
    bucket_scan<<<1, 1024, 0, stream>>>(ghist, bbase, bcur, NB, E);
    bucket_scatter<<<391, 256, 0, stream>>>(src, dstp, bcur, bsrc, bdl, E, NB);
    bucket_finalize<<<NB, 256, 0, stream>>>(bbase, bsrc, bdl, rowptr, ssrc, dinv, N, NB, E);

    const int AGG_BLOCKS = 2048;

    // ---- layer 0: x[N,128] -> hs0 ----
    gemm_hs<128><<<2048, 256, 0, stream>>>(x, W0, dinv, bufA, N);
    csr_agg_f4<<<AGG_BLOCKS, 256, 0, stream>>>(bufA, rowptr, ssrc, dinv, b0, bufB, N);

    // ---- layers 1-4 (xact in bufB -> hs in bufA -> xact in bufB) ----
    const float* Ws[4] = {W1, W2, W3, W4};
    const float* bs[4] = {b1, b2, b3, b4};
    for (int l = 0; l < 4; ++l) {
        gemm_hs<64><<<2048, 256, 0, stream>>>(bufB, Ws[l], dinv, bufA, N);
        csr_agg_f4<<<AGG_BLOCKS, 256, 0, stream>>>(bufA, rowptr, ssrc, dinv, bs[l], bufB, N);
    }

    // ---- layer 5: xact -> hs4[N,4] -> out ----
    gemm4_hs<<<1024, 256, 0, stream>>>(bufB, W5, dinv, bufA, N);
    csr_agg4<<<1024, 256, 0, stream>>>(bufA, rowptr, ssrc, dinv, b5, (float*)d_out, N);
}

// Round 12
// 550.966 us; speedup vs baseline: 1.6384x; 1.0429x over previous
//
#include <hip/hip_runtime.h>

// ---------------------------------------------------------------------------
// 6-layer GCN. Layer l: y = b + D^-1/2(A+I)D^-1/2 h ; x_next = lrelu(y)
// R11: R10 + masked full-width gather loop (no serial tail): every 16-edge
//      chunk issues all 4 wide gathers with clamped indices + 0/1 validity
//      weights. Agg grid 4096 blocks. Rest identical to R10 (best known).
// d_ws layout: rowptr[N+1] | dinv[N] | ssrc[E] | bufA[64N] | bufB[64N]
// Build temps alias into bufA (released before layer 0 writes bufA).
// ---------------------------------------------------------------------------

__device__ __forceinline__ float readlane_f(float v, int l) {
    union { float f; int i; } u;
    u.f = v;
    u.i = __builtin_amdgcn_readlane(u.i, l);
    return u.f;
}

// --- pass 1: coarse histogram of dst>>7 into NB buckets ---------------------
__global__ __launch_bounds__(256) void bucket_hist(const int* __restrict__ dst,
                                                   int* __restrict__ ghist,
                                                   int E, int NB) {
    __shared__ int h[1024];
    for (int i = threadIdx.x; i < NB; i += 256) h[i] = 0;
    __syncthreads();
    int i = blockIdx.x * blockDim.x + threadIdx.x;
    int stride = gridDim.x * blockDim.x;
    for (; i < E; i += stride) atomicAdd(&h[dst[i] >> 7], 1);
    __syncthreads();
    for (int j = threadIdx.x; j < NB; j += 256) {
        int c = h[j];
        if (c) atomicAdd(&ghist[j], c);
    }
}

// --- pass 2: exclusive scan of bucket counts (single block, 1024 thr) -------
__global__ void bucket_scan(const int* __restrict__ ghist, int* __restrict__ base,
                            int* __restrict__ cursor, int NB, int E) {
    int tid = threadIdx.x, lane = tid & 63, wid = tid >> 6;
    int v = (tid < NB) ? ghist[tid] : 0;
    int incl = v;
#pragma unroll
    for (int off = 1; off < 64; off <<= 1) {
        int t = __shfl_up(incl, off);
        if (lane >= off) incl += t;
    }
    __shared__ int ws[16];
    if (lane == 63) ws[wid] = incl;
    __syncthreads();
    if (tid == 0) {
        int run = 0;
        for (int i = 0; i < 16; ++i) { int t = ws[i]; ws[i] = run; run += t; }
    }
    __syncthreads();
    int excl = ws[wid] + incl - v;
    if (tid < NB) { base[tid] = excl; cursor[tid] = excl; }
    if (tid == 0) base[NB] = E;
}

// --- pass 3: scatter edges into bucket-sorted (bsrc, bdl) -------------------
__global__ __launch_bounds__(256) void bucket_scatter(
    const int* __restrict__ src, const int* __restrict__ dst,
    int* __restrict__ cursor, int* __restrict__ bsrc,
    unsigned char* __restrict__ bdl, int E, int NB) {
    __shared__ int h[1024];
    __shared__ int rb[1024];
    const int CH = 4096;
    for (int c0 = blockIdx.x * CH; c0 < E; c0 += gridDim.x * CH) {
        int cend = c0 + CH < E ? c0 + CH : E;
        for (int j = threadIdx.x; j < NB; j += 256) h[j] = 0;
        __syncthreads();
        for (int i = c0 + threadIdx.x; i < cend; i += 256)
            atomicAdd(&h[dst[i] >> 7], 1);
        __syncthreads();
        for (int j = threadIdx.x; j < NB; j += 256) {
            int c = h[j];
            rb[j] = c ? atomicAdd(&cursor[j], c) : 0;
            h[j] = 0;
        }
        __syncthreads();
        for (int i = c0 + threadIdx.x; i < cend; i += 256) {
            int d = dst[i];
            int b = d >> 7;
            int p = rb[b] + atomicAdd(&h[b], 1);
            bsrc[p] = src[i];
            bdl[p] = (unsigned char)(d & 127);
        }
        __syncthreads();
    }
}

// --- pass 4: per-bucket CSR finalize: rowptr, dinv, ssrc --------------------
__global__ __launch_bounds__(256) void bucket_finalize(
    const int* __restrict__ base, const int* __restrict__ bsrc,
    const unsigned char* __restrict__ bdl, int* __restrict__ rowptr,
    int* __restrict__ ssrc, float* __restrict__ dinv, int N, int NB, int E) {
    __shared__ int cnt[128];
    __shared__ int cur[128];
    __shared__ int w0sum;
    const int tid = threadIdx.x;
    const int lane = tid & 63;
    for (int b = blockIdx.x; b < NB; b += gridDim.x) {
        const int s = base[b], e = base[b + 1];
        const int d0 = b << 7;
        const int w = (N - d0 < 128) ? (N - d0) : 128;
        if (tid < 128) cnt[tid] = 0;
        __syncthreads();
        for (int i = s + tid; i < e; i += 256) atomicAdd(&cnt[bdl[i]], 1);
        __syncthreads();
        int v = (tid < 128) ? cnt[tid] : 0;
        int incl = v;
#pragma unroll
        for (int off = 1; off < 64; off <<= 1) {
            int t = __shfl_up(incl, off);
            if (lane >= off) incl += t;
        }
        if (tid == 63) w0sum = incl;
        __syncthreads();
        int excl = incl - v + ((tid >= 64 && tid < 128) ? w0sum : 0);
        if (tid < 128) cur[tid] = s + excl;
        if (tid < w) {
            rowptr[d0 + tid] = s + excl;
            dinv[d0 + tid] = rsqrtf((float)(v + 1));   // +1 self loop
        }
        __syncthreads();
        for (int i = s + tid; i < e; i += 256) {
            int p = atomicAdd(&cur[bdl[i]], 1);
            ssrc[p] = bsrc[i];
        }
        __syncthreads();
    }
    if (blockIdx.x == 0 && tid == 0) rowptr[N] = E;
}

// --- dense transform + dinv pre-scale (readlane broadcast, row-major):
//   hs[row,l] = dinv[row] * sum_k in[row,k] * W[k,l]
template <int K>
__global__ __launch_bounds__(256) void gemm_hs(
    const float* __restrict__ in, const float* __restrict__ W,
    const float* __restrict__ dinv, float* __restrict__ hs, int n) {
    const int lane = threadIdx.x & 63;
    const int gw = blockIdx.x * (blockDim.x >> 6) + (threadIdx.x >> 6);
    const int nw = gridDim.x * (blockDim.x >> 6);

    float wreg[K];
#pragma unroll
    for (int k = 0; k < K; ++k) wreg[k] = W[k * 64 + lane];

    for (int row = gw; row < n; row += nw) {
        float xv0 = in[(size_t)row * K + lane];
        float xv1 = 0.f;
        if (K == 128) xv1 = in[(size_t)row * K + 64 + lane];
        float a0 = 0.f, a1 = 0.f, a2 = 0.f, a3 = 0.f;
#pragma unroll
        for (int k = 0; k < 64; k += 4) {
            a0 = fmaf(readlane_f(xv0, k + 0), wreg[k + 0], a0);
            a1 = fmaf(readlane_f(xv0, k + 1), wreg[k + 1], a1);
            a2 = fmaf(readlane_f(xv0, k + 2), wreg[k + 2], a2);
            a3 = fmaf(readlane_f(xv0, k + 3), wreg[k + 3], a3);
        }
        if (K == 128) {
#pragma unroll
            for (int k = 0; k < 64; k += 4) {
                a0 = fmaf(readlane_f(xv1, k + 0), wreg[64 + k + 0], a0);
                a1 = fmaf(readlane_f(xv1, k + 1), wreg[64 + k + 1], a1);
                a2 = fmaf(readlane_f(xv1, k + 2), wreg[64 + k + 2], a2);
                a3 = fmaf(readlane_f(xv1, k + 3), wreg[64 + k + 3], a3);
            }
        }
        float acc = (a0 + a1) + (a2 + a3);
        hs[(size_t)row * 64 + lane] = dinv[row] * acc;
    }
}

// --- aggregation with wide masked gathers: wave = dst row, 64 lanes =
//     4 edges (g) x 16 float4-chunks (c). Every 16-edge chunk issues all 4
//     gathers with clamped indices + 0/1 weights (no serial tail).
__global__ __launch_bounds__(256) void csr_agg_f4(
    const float* __restrict__ hs, const int* __restrict__ rowptr,
    const int* __restrict__ ssrc, const float* __restrict__ dinv,
    const float* __restrict__ b, float* __restrict__ xact, int N) {
    const int lane = threadIdx.x & 63;
    const int g = lane >> 4;         // edge slot 0..3
    const int c = lane & 15;         // float4 chunk 0..15
    const int w = blockIdx.x * 4 + (threadIdx.x >> 6);
    const int nw = gridDim.x * 4;
    const float4 bl = ((const float4*)b)[c];

    for (int d = w; d < N; d += nw) {
        int e = __builtin_amdgcn_readfirstlane(rowptr[d]);
        const int end = __builtin_amdgcn_readfirstlane(rowptr[d + 1]);
        const int last = end - 1;
        float4 a0 = make_float4(0.f, 0.f, 0.f, 0.f), a1 = a0;
        if (g == 0) a0 = ((const float4*)(hs + (size_t)d * 64))[c];  // self loop
        for (; e < end; e += 16) {
            int i0 = e + g, i1 = e + 4 + g, i2 = e + 8 + g, i3 = e + 12 + g;
            float m0 = i0 < end ? 1.f : 0.f;
            float m1 = i1 < end ? 1.f : 0.f;
            float m2 = i2 < end ? 1.f : 0.f;
            float m3 = i3 < end ? 1.f : 0.f;
            i0 = i0 < last ? i0 : last;
            i1 = i1 < last ? i1 : last;
            i2 = i2 < last ? i2 : last;
            i3 = i3 < last ? i3 : last;
            int s0 = __builtin_nontemporal_load(ssrc + i0);
            int s1 = __builtin_nontemporal_load(ssrc + i1);
            int s2 = __builtin_nontemporal_load(ssrc + i2);
            int s3 = __builtin_nontemporal_load(ssrc + i3);
            float4 v0 = ((const float4*)(hs + (size_t)s0 * 64))[c];
            float4 v1 = ((const float4*)(hs + (size_t)s1 * 64))[c];
            float4 v2 = ((const float4*)(hs + (size_t)s2 * 64))[c];
            float4 v3 = ((const float4*)(hs + (size_t)s3 * 64))[c];
            a0.x = fmaf(m0, v0.x, a0.x); a0.y = fmaf(m0, v0.y, a0.y);
            a0.z = fmaf(m0, v0.z, a0.z); a0.w = fmaf(m0, v0.w, a0.w);
            a1.x = fmaf(m1, v1.x, a1.x); a1.y = fmaf(m1, v1.y, a1.y);
            a1.z = fmaf(m1, v1.z, a1.z); a1.w = fmaf(m1, v1.w, a1.w);
            a0.x = fmaf(m2, v2.x, a0.x); a0.y = fmaf(m2, v2.y, a0.y);
            a0.z = fmaf(m2, v2.z, a0.z); a0.w = fmaf(m2, v2.w, a0.w);
            a1.x = fmaf(m3, v3.x, a1.x); a1.y = fmaf(m3, v3.y, a1.y);
            a1.z = fmaf(m3, v3.z, a1.z); a1.w = fmaf(m3, v3.w, a1.w);
        }
        float4 acc = make_float4(a0.x + a1.x, a0.y + a1.y, a0.z + a1.z, a0.w + a1.w);
        // reduce over the 4 edge groups (lane ^16, ^32)
        acc.x += __shfl_xor(acc.x, 16); acc.y += __shfl_xor(acc.y, 16);
        acc.z += __shfl_xor(acc.z, 16); acc.w += __shfl_xor(acc.w, 16);
        acc.x += __shfl_xor(acc.x, 32); acc.y += __shfl_xor(acc.y, 32);
        acc.z += __shfl_xor(acc.z, 32); acc.w += __shfl_xor(acc.w, 32);
        const float di = dinv[d];
        float4 y;
        y.x = fmaf(di, acc.x, bl.x); y.y = fmaf(di, acc.y, bl.y);
        y.z = fmaf(di, acc.z, bl.z); y.w = fmaf(di, acc.w, bl.w);
        y.x = y.x >= 0.f ? y.x : 0.2f * y.x;
        y.y = y.y >= 0.f ? y.y : 0.2f * y.y;
        y.z = y.z >= 0.f ? y.z : 0.2f * y.z;
        y.w = y.w >= 0.f ? y.w : 0.2f * y.w;
        if (g == 0) ((float4*)(xact + (size_t)d * 64))[c] = y;
    }
}

// --- final layer gemm: pre-activated x -> W5[64,4] -> dinv scale ------------
__global__ __launch_bounds__(256) void gemm4_hs(
    const float* __restrict__ xact, const float* __restrict__ W,  // [64,4]
    const float* __restrict__ dinv, float* __restrict__ hs4, int n) {
    int i = blockIdx.x * blockDim.x + threadIdx.x;
    int stride = gridDim.x * blockDim.x;
    for (; i < n; i += stride) {
        const float4* xr = (const float4*)(xact + (size_t)i * 64);
        float a0 = 0.f, a1 = 0.f, a2 = 0.f, a3 = 0.f;
#pragma unroll
        for (int k4 = 0; k4 < 16; ++k4) {
            float4 xv = xr[k4];
            int k = k4 * 4;
            a0 = fmaf(xv.x, W[(k + 0) * 4 + 0], a0); a1 = fmaf(xv.x, W[(k + 0) * 4 + 1], a1);
            a2 = fmaf(xv.x, W[(k + 0) * 4 + 2], a2); a3 = fmaf(xv.x, W[(k + 0) * 4 + 3], a3);
            a0 = fmaf(xv.y, W[(k + 1) * 4 + 0], a0); a1 = fmaf(xv.y, W[(k + 1) * 4 + 1], a1);
            a2 = fmaf(xv.y, W[(k + 1) * 4 + 2], a2); a3 = fmaf(xv.y, W[(k + 1) * 4 + 3], a3);
            a0 = fmaf(xv.z, W[(k + 2) * 4 + 0], a0); a1 = fmaf(xv.z, W[(k + 2) * 4 + 1], a1);
            a2 = fmaf(xv.z, W[(k + 2) * 4 + 2], a2); a3 = fmaf(xv.z, W[(k + 2) * 4 + 3], a3);
            a0 = fmaf(xv.w, W[(k + 3) * 4 + 0], a0); a1 = fmaf(xv.w, W[(k + 3) * 4 + 1], a1);
            a2 = fmaf(xv.w, W[(k + 3) * 4 + 2], a2); a3 = fmaf(xv.w, W[(k + 3) * 4 + 3], a3);
        }
        float di = dinv[i];
        ((float4*)hs4)[i] = make_float4(di * a0, di * a1, di * a2, di * a3);
    }
}

// --- final aggregation over pre-scaled hs4: out = b + dinv[d]*(self + sum) --
__global__ __launch_bounds__(256) void csr_agg4(
    const float* __restrict__ hs4, const int* __restrict__ rowptr,
    const int* __restrict__ ssrc, const float* __restrict__ dinv,
    const float* __restrict__ b, float* __restrict__ out, int n) {
    int i = blockIdx.x * blockDim.x + threadIdx.x;
    int stride = gridDim.x * blockDim.x;
    float b0 = b[0], b1 = b[1], b2 = b[2], b3 = b[3];
    for (; i < n; i += stride) {
        float4 hv = ((const float4*)hs4)[i];
        float a0 = hv.x, a1 = hv.y, a2 = hv.z, a3 = hv.w;   // self loop
        int e = rowptr[i], end = rowptr[i + 1];
        for (; e < end; ++e) {
            int s = ssrc[e];
            float4 v = ((const float4*)hs4)[s];
            a0 += v.x; a1 += v.y; a2 += v.z; a3 += v.w;
        }
        float di = dinv[i];
        ((float4*)out)[i] = make_float4(fmaf(di, a0, b0), fmaf(di, a1, b1),
                                        fmaf(di, a2, b2), fmaf(di, a3, b3));
    }
}

static inline size_t al64(size_t x) { return (x + 63) & ~(size_t)63; }

extern "C" void kernel_launch(void* const* d_in, const int* in_sizes, int n_in,
                              void* d_out, int out_size, void* d_ws, size_t ws_size,
                              hipStream_t stream) {
    const float* x  = (const float*)d_in[0];
    const int* ei   = (const int*)d_in[1];
    const float* W0 = (const float*)d_in[2];
    const float* b0 = (const float*)d_in[3];
    const float* W1 = (const float*)d_in[4];
    const float* b1 = (const float*)d_in[5];
    const float* W2 = (const float*)d_in[6];
    const float* b2 = (const float*)d_in[7];
    const float* W3 = (const float*)d_in[8];
    const float* b3 = (const float*)d_in[9];
    const float* W4 = (const float*)d_in[10];
    const float* b4 = (const float*)d_in[11];
    const float* W5 = (const float*)d_in[12];
    const float* b5 = (const float*)d_in[13];

    const int N = in_sizes[0] / 128;
    const int E = in_sizes[1] / 2;
    const int* src  = ei;       // edge_index[0] = message sources
    const int* dstp = ei + E;   // edge_index[1] = aggregation targets
    const int NB = (N + 127) >> 7;   // dst buckets of 128 ids (NB <= 1024)

    float* ws = (float*)d_ws;
    size_t off = 0;
    int*   rowptr = (int*)(ws + off);   off += al64((size_t)N + 1);
    float* dinv   = ws + off;           off += al64((size_t)N);
    int*   ssrc   = (int*)(ws + off);   off += al64((size_t)E);
    float* bufA   = ws + off;           off += (size_t)64 * N;
    float* bufB   = ws + off;

    // build temps alias into bufA (released before layer 0 writes bufA)
    int* ghist = (int*)bufA;                       // [1024]
    int* bbase = ghist + 1024;                     // [NB+1]
    int* bcur  = bbase + 1088;                     // [NB]
    int* bsrc  = (int*)(bufA + 4096);              // [E]
    unsigned char* bdl = (unsigned char*)(bsrc + E);  // [E]

    // ---- graph build (bucketed counting sort) ----
    hipMemsetAsync(ghist, 0, 1024 * sizeof(int), stream);
    bucket_hist<<<391, 256, 0, stream>>>(dstp, ghist, E, NB);
    bucket_scan<<<1, 1024, 0, stream>>>(ghist, bbase, bcur, NB, E);
    bucket_scatter<<<391, 256, 0, stream>>>(src, dstp, bcur, bsrc, bdl, E, NB);
    bucket_finalize<<<NB, 256, 0, stream>>>(bbase, bsrc, bdl, rowptr, ssrc, dinv, N, NB, E);

    const int AGG_BLOCKS = 4096;

    // ---- layer 0: x[N,128] -> hs0 ----
    gemm_hs<128><<<2048, 256, 0, stream>>>(x, W0, dinv, bufA, N);
    csr_agg_f4<<<AGG_BLOCKS, 256, 0, stream>>>(bufA, rowptr, ssrc, dinv, b0, bufB, N);

    // ---- layers 1-4 (xact in bufB -> hs in bufA -> xact in bufB) ----
    const float* Ws[4] = {W1, W2, W3, W4};
    const float* bs[4] = {b1, b2, b3, b4};
    for (int l = 0; l < 4; ++l) {
        gemm_hs<64><<<2048, 256, 0, stream>>>(bufB, Ws[l], dinv, bufA, N);
        csr_agg_f4<<<AGG_BLOCKS, 256, 0, stream>>>(bufA, rowptr, ssrc, dinv, bs[l], bufB, N);
    }

    // ---- layer 5: xact -> hs4[N,4] -> out ----
    gemm4_hs<<<1024, 256, 0, stream>>>(bufB, W5, dinv, bufA, N);
    csr_agg4<<<1024, 256, 0, stream>>>(bufA, rowptr, ssrc, dinv, b5, (float*)d_out, N);
}